// Round 4
// baseline (161.424 us; speedup 1.0000x reference)
//
#include <hip/hip_runtime.h>
#include <cmath>

// Problem constants (fixed by the reference)
constexpr int T_DIM = 4096;
constexpr int H_DIM = 1024;
constexpr int E_DIM = 8;
constexpr int I_DIM = 512;   // 4096 / 8
constexpr int V_DIM = 32000;

typedef _Float16 half_t;
typedef __attribute__((ext_vector_type(8))) _Float16 halfx8;
typedef __attribute__((ext_vector_type(4))) _Float16 halfx4;
typedef __attribute__((ext_vector_type(4))) float floatx4;

// async global->LDS, 16 B per lane; LDS dest is wave-uniform base + lane*16
#define GLOAD16(g, l)                                                        \
    __builtin_amdgcn_global_load_lds(                                        \
        (const __attribute__((address_space(1))) void*)(g),                  \
        (__attribute__((address_space(3))) void*)(l), 16, 0, 0)

// ---------------------------------------------------------------------------
// Workspace layout (bytes)
// counts padded: counts[e] lives at int index e*16 (separate 64B lines so the
// 8 fetch-add chains don't ping-pong one cache line).
// ---------------------------------------------------------------------------
constexpr int  CNT_STRIDE  = 16;                                          // ints
constexpr size_t OFF_COUNTS = 0;                                          // E*16 ints (512 B)
constexpr size_t OFF_EID    = 1024;                                       // T ints (16 KB)
constexpr size_t OFF_TOKL   = OFF_EID + (size_t)T_DIM * 4;                // E*T ints (128 KB)
constexpr size_t OFF_XB     = OFF_TOKL + (size_t)E_DIM * T_DIM * 4;       // T*H f16 (8 MB)
constexpr size_t OFF_GUPT   = OFF_XB + (size_t)T_DIM * H_DIM * 2;         // E*2I*H f16 (16 MB)
constexpr size_t OFF_DOWNT  = OFF_GUPT + (size_t)E_DIM * 2 * I_DIM * H_DIM * 2; // E*H*I f16 (8 MB)
constexpr size_t OFF_INTER  = OFF_DOWNT + (size_t)E_DIM * H_DIM * I_DIM * 2;    // T*I f16 (4 MB)

// ---------------------------------------------------------------------------
// Prep: one launch, grid (8, 256, 4). blockIdx.x round-robins the 8 XCDs
// (linear dispatch id = bx + 8*by + 2048*bz), so bx IS the XCD.
//   z == 0      : gup transpose, expert = bx -> expert e's panel is produced
//                 ON XCD e, landing gupT[e] in the same L2 that gemm1's
//                 XCD-e blocks will read.
//   z == 1      : x -> f16 convert. ROUND-3 BUG FIXED: each of the 512 useful
//                 blocks owns 8192 floats -> needs 4 iterations of
//                 256 thr x 8 floats (round 3 did 1 iter = 1/4 coverage,
//                 absmax 3.69 from stale-poison xb).
//   z in [2,4)  : routing logits, ONE BLOCK PER TOKEN (round-1 post-mortem:
//                 64-token/block serialized loads -> 86us latency-bound; this
//                 form issues the mu row as one parallel float4 wave).
// Down-transpose lives in gemm1's launch (z>=64 there, bx=e affinity there).
// ---------------------------------------------------------------------------
__global__ __launch_bounds__(256) void prep_kernel(
    const float* __restrict__ x, const float* __restrict__ gup,
    const float* __restrict__ mu, const int* __restrict__ token_ids,
    const float* __restrict__ mu_w, half_t* __restrict__ xb,
    half_t* __restrict__ gupT, int* __restrict__ expert_id)
{
    const int z = blockIdx.z, bx = blockIdx.x, by = blockIdx.y;
    const int tid = threadIdx.x;

    if (z >= 2) {  // routing logits: one block per token
        const int t = ((z - 2) * 256 + by) * 8 + bx;

        const float4 m = *(const float4*)&mu[(size_t)t * H_DIM + tid * 4];
        float acc[E_DIM];
#pragma unroll
        for (int e = 0; e < E_DIM; ++e) {
            const float4 w = *(const float4*)&mu_w[e * H_DIM + tid * 4];
            acc[e] = m.x * w.x + m.y * w.y + m.z * w.z + m.w * w.w;
        }
#pragma unroll
        for (int e = 0; e < E_DIM; ++e) {
#pragma unroll
            for (int off = 32; off > 0; off >>= 1)
                acc[e] += __shfl_down(acc[e], off, 64);
        }
        __shared__ float part[4][E_DIM];
        const int lane = tid & 63, w = tid >> 6;
        if (lane == 0) {
#pragma unroll
            for (int e = 0; e < E_DIM; ++e) part[w][e] = acc[e];
        }
        __syncthreads();
        if (tid == 0) {
            int tk = token_ids[t];
            tk = min(max(tk, 0), V_DIM - 1);
            const int be = tk & (E_DIM - 1);
            float best = -1e30f; int bi = 0;
#pragma unroll
            for (int e = 0; e < E_DIM; ++e) {
                const float c = part[0][e] + part[1][e] + part[2][e] + part[3][e]
                              + (e == be ? 10.f : 0.f);
                if (c > best) { best = c; bi = e; }  // strict > = first max (jnp.argmax)
            }
            expert_id[t] = bi;
        }
        return;
    }

    if (z == 1) {  // convert x -> f16: 512 blocks x 8192 floats (4 x 2048)
        const int idx = by * 8 + bx;
        if (idx >= 512) return;
#pragma unroll
        for (int p = 0; p < 4; ++p) {
            const size_t i = (size_t)idx * 8192 + p * 2048 + tid * 8;
            const float4 v0 = *(const float4*)&x[i];
            const float4 v1 = *(const float4*)&x[i + 4];
            halfx8 h = { (half_t)v0.x, (half_t)v0.y, (half_t)v0.z, (half_t)v0.w,
                         (half_t)v1.x, (half_t)v1.y, (half_t)v1.z, (half_t)v1.w };
            *(halfx8*)&xb[i] = h;
        }
        return;
    }

    // z == 0: gup transpose, e = bx (== XCD). K = H = 1024, N = 2I = 1024.
    __shared__ float tile[64][65];
    const float* se = gup + (size_t)bx * H_DIM * (2 * I_DIM);
    half_t* de = gupT + (size_t)bx * (2 * I_DIM) * H_DIM;
    constexpr int N = 1024, K = H_DIM;
    const int n0 = (by & 15) * 64, k0 = (by >> 4) * 64;
    const int c4 = (tid & 15) * 4, r0 = tid >> 4;
#pragma unroll
    for (int p = 0; p < 4; ++p) {
        const int r = r0 + p * 16;
        const float4 v = *(const float4*)&se[(size_t)(k0 + r) * N + n0 + c4];
        tile[r][c4 + 0] = v.x; tile[r][c4 + 1] = v.y;
        tile[r][c4 + 2] = v.z; tile[r][c4 + 3] = v.w;
    }
    __syncthreads();
#pragma unroll
    for (int p = 0; p < 4; ++p) {
        const int n = r0 + p * 16;
        const int kc = c4;
        halfx4 h = { (half_t)tile[kc + 0][n], (half_t)tile[kc + 1][n],
                     (half_t)tile[kc + 2][n], (half_t)tile[kc + 3][n] };
        *(halfx4*)&de[(size_t)(n0 + n) * K + k0 + kc] = h;
    }
}

// ---------------------------------------------------------------------------
// Scatter: 64 blocks x 64 tokens, one wave each. Ballot histogram + ONE
// global fetch-add per (block, expert) -> 512 atomics on 8 padded lines,
// chains run in parallel across blocks. Order within a bucket is irrelevant.
// ---------------------------------------------------------------------------
__global__ __launch_bounds__(64) void scatter_kernel(
    const int* __restrict__ expert_id, int* __restrict__ counts,
    int* __restrict__ tok_list)
{
    const int tid = threadIdx.x;
    const int t = blockIdx.x * 64 + tid;
    const int mye = expert_id[t];
#pragma unroll
    for (int e = 0; e < E_DIM; ++e) {
        const unsigned long long mask = __ballot(mye == e);
        if (mye == e) {
            const int leader = __builtin_ctzll(mask);
            const int rank = (int)__popcll(mask & ((1ull << tid) - 1ull));
            int base = 0;
            if (tid == leader)
                base = atomicAdd(&counts[e * CNT_STRIDE], (int)__popcll(mask));
            base = __shfl(base, leader, 64);
            tok_list[e * T_DIM + base + rank] = t;
        }
    }
}

// ---------------------------------------------------------------------------
// MFMA GEMM 1: inter = silu(x@Wg) * (x@Wu). Tile 64 tok x (64g + 64u), BK=64.
// EXACT round-5 GEMM configuration: single-buffer, compiler-scheduled waits,
// blockIdx.x = expert -> XCD affinity (expert e's 2MB weights + ~1MB token
// rows fit XCD e's 4MB L2 — the round-5 win).
// blockIdx.z in [64,80) = down-proj transpose tiles (pure streaming, fills
// this kernel's idle issue slots; same x=e affinity: downT[e] is produced on
// XCD e for gemm2). LDS overlaid via a raw smem block.
// ---------------------------------------------------------------------------
__global__ __launch_bounds__(256) void gemm1_mfma_kernel(
    const half_t* __restrict__ xb, const half_t* __restrict__ gupT,
    const float* __restrict__ down, half_t* __restrict__ downT,
    const int* __restrict__ counts, const int* __restrict__ tok_list,
    half_t* __restrict__ inter)
{
    __shared__ __align__(16) char smraw[64 * 64 * 2 + 128 * 64 * 2 + 64 * 4];
    const int tid = threadIdx.x;
    const int e = blockIdx.x;              // expert == XCD affinity

    if (blockIdx.z >= 64) {  // down transpose: K = I = 512, N = H = 1024
        float (*tile)[65] = (float (*)[65])smraw;   // 64*65*4 = 16.6KB <= 24.8KB
        const float* se = down + (size_t)e * I_DIM * H_DIM;
        half_t* de = downT + (size_t)e * H_DIM * I_DIM;
        const int n0 = (blockIdx.z - 64) * 64, k0 = blockIdx.y * 64;
        const int c4 = (tid & 15) * 4, r0 = tid >> 4;
#pragma unroll
        for (int p = 0; p < 4; ++p) {
            const int r = r0 + p * 16;
            const float4 v = *(const float4*)&se[(size_t)(k0 + r) * H_DIM + n0 + c4];
            tile[r][c4 + 0] = v.x; tile[r][c4 + 1] = v.y;
            tile[r][c4 + 2] = v.z; tile[r][c4 + 3] = v.w;
        }
        __syncthreads();
#pragma unroll
        for (int p = 0; p < 4; ++p) {
            const int n = r0 + p * 16;
            const int kc = c4;
            halfx4 h = { (half_t)tile[kc + 0][n], (half_t)tile[kc + 1][n],
                         (half_t)tile[kc + 2][n], (half_t)tile[kc + 3][n] };
            *(halfx4*)&de[(size_t)(n0 + n) * I_DIM + k0 + kc] = h;
        }
        return;
    }

    const int count = counts[e * CNT_STRIDE];
    const int m0 = blockIdx.z * 64;
    if (m0 >= count) return;
    const int n0 = blockIdx.y * 64;        // gate col block

    half_t* const As = (half_t*)smraw;                      // 64x64
    half_t* const Bs = (half_t*)(smraw + 64 * 64 * 2);      // 128x64
    int* const toks = (int*)(smraw + 64 * 64 * 2 + 128 * 64 * 2);

    if (tid < 64) {
        const int m = m0 + tid;
        toks[tid] = (m < count) ? tok_list[e * T_DIM + m] : -1;
    }
    __syncthreads();

    const half_t* We = gupT + (size_t)e * (2 * I_DIM) * H_DIM;

    const int lane = tid & 63;
    const int w = tid >> 6;
    const int lr = lane >> 3, lc = lane & 7;

    // per-lane staging pointers (row fixed across K-loop)
    const half_t* aptr[2]; const half_t* bptr[4];
    half_t *alds[2], *blds[4];
#pragma unroll
    for (int j = 0; j < 2; ++j) {                 // A rows [w*16, w*16+16)
        const int r = w * 16 + j * 8 + lr;
        const int cg = lc ^ (r & 7);
        const int tk = toks[r];
        aptr[j] = xb + (size_t)(tk < 0 ? 0 : tk) * H_DIM + cg * 8;
        alds[j] = &As[(w * 16 + j * 8) * 64];
    }
#pragma unroll
    for (int j = 0; j < 4; ++j) {                 // B rows [w*32, w*32+32)
        const int n = w * 32 + j * 8 + lr;
        const int col = (n < 64) ? (n0 + n) : (I_DIM + n0 + (n - 64));
        const int cg = lc ^ (n & 7);
        bptr[j] = We + (size_t)col * H_DIM + cg * 8;
        blds[j] = &Bs[(w * 32 + j * 8) * 64];
    }

    const floatx4 fzero = {0.f, 0.f, 0.f, 0.f};
    floatx4 accg[2][2], accu[2][2];
#pragma unroll
    for (int i = 0; i < 2; ++i)
#pragma unroll
        for (int j = 0; j < 2; ++j) { accg[i][j] = fzero; accu[i][j] = fzero; }

    const int wr = w >> 1, wc = w & 1;
    const int fm = lane & 15, q = lane >> 4;
    const int fm7 = fm & 7;

    for (int k0 = 0; k0 < H_DIM; k0 += 64) {
#pragma unroll
        for (int j = 0; j < 2; ++j) GLOAD16(aptr[j] + k0, alds[j]);
#pragma unroll
        for (int j = 0; j < 4; ++j) GLOAD16(bptr[j] + k0, blds[j]);
        __syncthreads();

#pragma unroll
        for (int ks = 0; ks < 2; ++ks) {
            const int swz = ((ks * 4 + q) ^ fm7) * 8;   // halves
            const halfx8 a0 = *(const halfx8*)&As[(32 * wr + fm) * 64 + swz];
            const halfx8 a1 = *(const halfx8*)&As[(32 * wr + 16 + fm) * 64 + swz];
#pragma unroll
            for (int ct = 0; ct < 2; ++ct) {
                const int ng = wc * 32 + ct * 16 + fm;
                const halfx8 bg = *(const halfx8*)&Bs[ng * 64 + swz];
                const halfx8 bu = *(const halfx8*)&Bs[(64 + ng) * 64 + swz];
                accg[0][ct] = __builtin_amdgcn_mfma_f32_16x16x32_f16(a0, bg, accg[0][ct], 0, 0, 0);
                accg[1][ct] = __builtin_amdgcn_mfma_f32_16x16x32_f16(a1, bg, accg[1][ct], 0, 0, 0);
                accu[0][ct] = __builtin_amdgcn_mfma_f32_16x16x32_f16(a0, bu, accu[0][ct], 0, 0, 0);
                accu[1][ct] = __builtin_amdgcn_mfma_f32_16x16x32_f16(a1, bu, accu[1][ct], 0, 0, 0);
            }
        }
        __syncthreads();
    }

    // C/D layout: col = lane&15, row = q*4 + reg
#pragma unroll
    for (int rt = 0; rt < 2; ++rt)
#pragma unroll
        for (int r = 0; r < 4; ++r) {
            const int row = 32 * wr + 16 * rt + q * 4 + r;
            const int tk = toks[row];
            if (tk < 0) continue;
#pragma unroll
            for (int ct = 0; ct < 2; ++ct) {
                const float g = accg[rt][ct][r];
                const float u = accu[rt][ct][r];
                const float s = g / (1.f + __expf(-g)) * u;
                inter[(size_t)tk * I_DIM + n0 + wc * 32 + ct * 16 + fm] = (half_t)s;
            }
        }
}

// ---------------------------------------------------------------------------
// MFMA GEMM 2: out = inter @ down. Tile 64 x 128, BK=64, same staging scheme.
// EXACT round-5 configuration. Same expert==blockIdx.x XCD-affinity grid.
// ---------------------------------------------------------------------------
__global__ __launch_bounds__(256) void gemm2_mfma_kernel(
    const half_t* __restrict__ inter, const half_t* __restrict__ downT,
    const int* __restrict__ counts, const int* __restrict__ tok_list,
    float* __restrict__ out)
{
    const int e = blockIdx.x;              // expert == XCD affinity
    const int count = counts[e * CNT_STRIDE];
    const int m0 = blockIdx.z * 64;
    if (m0 >= count) return;
    const int n0 = blockIdx.y * 128;

    __shared__ __align__(16) half_t As[64 * 64];
    __shared__ __align__(16) half_t Bs[128 * 64];
    __shared__ int toks[64];

    const int tid = threadIdx.x;
    if (tid < 64) {
        const int m = m0 + tid;
        toks[tid] = (m < count) ? tok_list[e * T_DIM + m] : -1;
    }
    __syncthreads();

    const half_t* De = downT + (size_t)e * H_DIM * I_DIM;

    const int lane = tid & 63;
    const int w = tid >> 6;
    const int lr = lane >> 3, lc = lane & 7;

    const half_t* aptr[2]; const half_t* bptr[4];
    half_t *alds[2], *blds[4];
#pragma unroll
    for (int j = 0; j < 2; ++j) {
        const int r = w * 16 + j * 8 + lr;
        const int cg = lc ^ (r & 7);
        const int tk = toks[r];
        aptr[j] = inter + (size_t)(tk < 0 ? 0 : tk) * I_DIM + cg * 8;
        alds[j] = &As[(w * 16 + j * 8) * 64];
    }
#pragma unroll
    for (int j = 0; j < 4; ++j) {
        const int n = w * 32 + j * 8 + lr;
        const int cg = lc ^ (n & 7);
        bptr[j] = De + (size_t)(n0 + n) * I_DIM + cg * 8;
        blds[j] = &Bs[(w * 32 + j * 8) * 64];
    }

    const floatx4 fzero = {0.f, 0.f, 0.f, 0.f};
    floatx4 acc[2][4];
#pragma unroll
    for (int i = 0; i < 2; ++i)
#pragma unroll
        for (int j = 0; j < 4; ++j) acc[i][j] = fzero;

    const int wr = w >> 1, wc = w & 1;
    const int fm = lane & 15, q = lane >> 4;
    const int fm7 = fm & 7;

    for (int k0 = 0; k0 < I_DIM; k0 += 64) {
#pragma unroll
        for (int j = 0; j < 2; ++j) GLOAD16(aptr[j] + k0, alds[j]);
#pragma unroll
        for (int j = 0; j < 4; ++j) GLOAD16(bptr[j] + k0, blds[j]);
        __syncthreads();

#pragma unroll
        for (int ks = 0; ks < 2; ++ks) {
            const int swz = ((ks * 4 + q) ^ fm7) * 8;
            const halfx8 a0 = *(const halfx8*)&As[(32 * wr + fm) * 64 + swz];
            const halfx8 a1 = *(const halfx8*)&As[(32 * wr + 16 + fm) * 64 + swz];
#pragma unroll
            for (int ct = 0; ct < 4; ++ct) {
                const halfx8 b = *(const halfx8*)&Bs[(wc * 64 + ct * 16 + fm) * 64 + swz];
                acc[0][ct] = __builtin_amdgcn_mfma_f32_16x16x32_f16(a0, b, acc[0][ct], 0, 0, 0);
                acc[1][ct] = __builtin_amdgcn_mfma_f32_16x16x32_f16(a1, b, acc[1][ct], 0, 0, 0);
            }
        }
        __syncthreads();
    }

#pragma unroll
    for (int rt = 0; rt < 2; ++rt)
#pragma unroll
        for (int r = 0; r < 4; ++r) {
            const int row = 32 * wr + 16 * rt + q * 4 + r;
            const int tk = toks[row];
            if (tk < 0) continue;
#pragma unroll
            for (int ct = 0; ct < 4; ++ct)
                out[(size_t)tk * H_DIM + n0 + wc * 64 + ct * 16 + fm] = acc[rt][ct][r];
        }
}

// ---------------------------------------------------------------------------
extern "C" void kernel_launch(void* const* d_in, const int* in_sizes, int n_in,
                              void* d_out, int out_size, void* d_ws, size_t ws_size,
                              hipStream_t stream)
{
    const float* x         = (const float*)d_in[0];
    const int*   token_ids = (const int*)  d_in[1];
    const float* mu        = (const float*)d_in[2];
    const float* gup       = (const float*)d_in[3];
    const float* down      = (const float*)d_in[4];
    const float* mu_w      = (const float*)d_in[5];
    float* out = (float*)d_out;

    char* ws = (char*)d_ws;
    int*    counts    = (int*)(ws + OFF_COUNTS);
    int*    expert_id = (int*)(ws + OFF_EID);
    int*    tok_list  = (int*)(ws + OFF_TOKL);
    half_t* xb        = (half_t*)(ws + OFF_XB);
    half_t* gupT      = (half_t*)(ws + OFF_GUPT);
    half_t* downT     = (half_t*)(ws + OFF_DOWNT);
    half_t* inter     = (half_t*)(ws + OFF_INTER);

    // counts must start at 0 for the scatter fetch-adds (ws is poisoned).
    hipMemsetAsync(counts, 0, E_DIM * CNT_STRIDE * sizeof(int), stream);

    // grid (8,256,4): bx == XCD. z=0: gup transpose (expert=bx, produced on
    // XCD bx). z=1: x->f16 (512 blocks x 4 iters). z=2..3: routing.
    prep_kernel<<<dim3(8, 256, 4), 256, 0, stream>>>(
        x, gup, mu, token_ids, mu_w, xb, gupT, expert_id);
    scatter_kernel<<<64, 64, 0, stream>>>(expert_id, counts, tok_list);
    // z<64: gemm m-blocks (early-exit past count); z in [64,80): down-proj
    // transpose tiles overlapped with the gemm. expert on blockIdx.x =>
    // consecutive linear ids round-robin the 8 XCDs, pinning expert e to XCD e.
    gemm1_mfma_kernel<<<dim3(E_DIM, 8, 80), 256, 0, stream>>>(
        xb, gupT, down, downT, counts, tok_list, inter);
    gemm2_mfma_kernel<<<dim3(E_DIM, 8, T_DIM / 64), 256, 0, stream>>>(
        inter, downT, counts, tok_list, out);
}

// Round 5
// 158.597 us; speedup vs baseline: 1.0178x; 1.0178x over previous
//
#include <hip/hip_runtime.h>
#include <cmath>

// Problem constants (fixed by the reference)
constexpr int T_DIM = 4096;
constexpr int H_DIM = 1024;
constexpr int E_DIM = 8;
constexpr int I_DIM = 512;   // 4096 / 8
constexpr int V_DIM = 32000;

typedef _Float16 half_t;
typedef __attribute__((ext_vector_type(8))) _Float16 halfx8;
typedef __attribute__((ext_vector_type(4))) _Float16 halfx4;
typedef __attribute__((ext_vector_type(4))) float floatx4;

// async global->LDS, 16 B per lane; LDS dest is wave-uniform base + lane*16
#define GLOAD16(g, l)                                                        \
    __builtin_amdgcn_global_load_lds(                                        \
        (const __attribute__((address_space(1))) void*)(g),                  \
        (__attribute__((address_space(3))) void*)(l), 16, 0, 0)

// ---------------------------------------------------------------------------
// Workspace layout (bytes)
// ---------------------------------------------------------------------------
constexpr int  CNT_STRIDE  = 16;                                          // ints
constexpr size_t OFF_COUNTS = 0;                                          // E*16 ints (512 B)
constexpr size_t OFF_EID    = 1024;                                       // T ints (16 KB)
constexpr size_t OFF_TOKL   = OFF_EID + (size_t)T_DIM * 4;                // E*T ints (128 KB)
constexpr size_t OFF_XB     = OFF_TOKL + (size_t)E_DIM * T_DIM * 4;       // T*H f16 (8 MB)
constexpr size_t OFF_GUPT   = OFF_XB + (size_t)T_DIM * H_DIM * 2;         // E*2I*H f16 (16 MB)
constexpr size_t OFF_DOWNT  = OFF_GUPT + (size_t)E_DIM * 2 * I_DIM * H_DIM * 2; // E*H*I f16 (8 MB)
constexpr size_t OFF_INTER  = OFF_DOWNT + (size_t)E_DIM * H_DIM * I_DIM * 2;    // T*I f16 (4 MB)

// ---------------------------------------------------------------------------
// Prep: one launch, grid (8, 256, 4). blockIdx.x round-robins the 8 XCDs.
//   z == 0      : gup transpose, expert = bx (XCD-affine producer; R4: neutral
//                 but harmless — kept).
//   z == 1      : x -> f16 convert (512 blocks x 4 x 2048 floats).
//   z in [2,4)  : routing logits, ONE BLOCK PER TOKEN (R1 post-mortem: multi-
//                 token blocks serialize mu loads -> 86us latency-bound).
// Down-transpose lives in gemm1's launch (z>=64 there).
// GEMM bodies stay at the round-5 optimum (R6/R7 regressions).
// ---------------------------------------------------------------------------
__global__ __launch_bounds__(256) void prep_kernel(
    const float* __restrict__ x, const float* __restrict__ gup,
    const float* __restrict__ mu, const int* __restrict__ token_ids,
    const float* __restrict__ mu_w, half_t* __restrict__ xb,
    half_t* __restrict__ gupT, int* __restrict__ expert_id)
{
    const int z = blockIdx.z, bx = blockIdx.x, by = blockIdx.y;
    const int tid = threadIdx.x;

    if (z >= 2) {  // routing logits: one block per token
        const int t = ((z - 2) * 256 + by) * 8 + bx;

        const float4 m = *(const float4*)&mu[(size_t)t * H_DIM + tid * 4];
        float acc[E_DIM];
#pragma unroll
        for (int e = 0; e < E_DIM; ++e) {
            const float4 w = *(const float4*)&mu_w[e * H_DIM + tid * 4];
            acc[e] = m.x * w.x + m.y * w.y + m.z * w.z + m.w * w.w;
        }
#pragma unroll
        for (int e = 0; e < E_DIM; ++e) {
#pragma unroll
            for (int off = 32; off > 0; off >>= 1)
                acc[e] += __shfl_down(acc[e], off, 64);
        }
        __shared__ float part[4][E_DIM];
        const int lane = tid & 63, w = tid >> 6;
        if (lane == 0) {
#pragma unroll
            for (int e = 0; e < E_DIM; ++e) part[w][e] = acc[e];
        }
        __syncthreads();
        if (tid == 0) {
            int tk = token_ids[t];
            tk = min(max(tk, 0), V_DIM - 1);
            const int be = tk & (E_DIM - 1);
            float best = -1e30f; int bi = 0;
#pragma unroll
            for (int e = 0; e < E_DIM; ++e) {
                const float c = part[0][e] + part[1][e] + part[2][e] + part[3][e]
                              + (e == be ? 10.f : 0.f);
                if (c > best) { best = c; bi = e; }  // strict > = first max (jnp.argmax)
            }
            expert_id[t] = bi;
        }
        return;
    }

    if (z == 1) {  // convert x -> f16: 512 blocks x 8192 floats (4 x 2048)
        const int idx = by * 8 + bx;
        if (idx >= 512) return;
#pragma unroll
        for (int p = 0; p < 4; ++p) {
            const size_t i = (size_t)idx * 8192 + p * 2048 + tid * 8;
            const float4 v0 = *(const float4*)&x[i];
            const float4 v1 = *(const float4*)&x[i + 4];
            halfx8 h = { (half_t)v0.x, (half_t)v0.y, (half_t)v0.z, (half_t)v0.w,
                         (half_t)v1.x, (half_t)v1.y, (half_t)v1.z, (half_t)v1.w };
            *(halfx8*)&xb[i] = h;
        }
        return;
    }

    // z == 0: gup transpose, e = bx (== XCD). K = H = 1024, N = 2I = 1024.
    __shared__ float tile[64][65];
    const float* se = gup + (size_t)bx * H_DIM * (2 * I_DIM);
    half_t* de = gupT + (size_t)bx * (2 * I_DIM) * H_DIM;
    constexpr int N = 1024, K = H_DIM;
    const int n0 = (by & 15) * 64, k0 = (by >> 4) * 64;
    const int c4 = (tid & 15) * 4, r0 = tid >> 4;
#pragma unroll
    for (int p = 0; p < 4; ++p) {
        const int r = r0 + p * 16;
        const float4 v = *(const float4*)&se[(size_t)(k0 + r) * N + n0 + c4];
        tile[r][c4 + 0] = v.x; tile[r][c4 + 1] = v.y;
        tile[r][c4 + 2] = v.z; tile[r][c4 + 3] = v.w;
    }
    __syncthreads();
#pragma unroll
    for (int p = 0; p < 4; ++p) {
        const int n = r0 + p * 16;
        const int kc = c4;
        halfx4 h = { (half_t)tile[kc + 0][n], (half_t)tile[kc + 1][n],
                     (half_t)tile[kc + 2][n], (half_t)tile[kc + 3][n] };
        *(halfx4*)&de[(size_t)(n0 + n) * K + k0 + kc] = h;
    }
}

// ---------------------------------------------------------------------------
// Scatter, ZERO-ATOMIC (round-5 change): one block per expert, 1024 threads.
// Round-4 post-mortem: the ballot+fetch-add scatter serializes 64-deep
// atomic chains on 8 cache lines (~200-400ns per contended cross-XCD RMW
// = est 15-25us of pure latency). Here each block scans all 4096 ids in 4
// rounds and compacts its own bucket with a ballot + wave-count LDS prefix:
// no global atomics anywhere; counts becomes a plain store (memset dispatch
// dropped). Side benefit: tok_list is token-sorted per bucket -> monotone
// xb/inter row reads in the GEMMs.
// ---------------------------------------------------------------------------
__global__ __launch_bounds__(1024) void scatter_kernel(
    const int* __restrict__ expert_id, int* __restrict__ counts,
    int* __restrict__ tok_list)
{
    const int e = blockIdx.x;
    const int tid = threadIdx.x;
    const int lane = tid & 63, wv = tid >> 6;   // 16 waves
    __shared__ int wcnt[16];
    int base = 0;
#pragma unroll
    for (int r = 0; r < 4; ++r) {
        const int t = r * 1024 + tid;
        const bool m = (expert_id[t] == e);
        const unsigned long long mask = __ballot(m);
        const int wrank = (int)__popcll(mask & ((1ull << lane) - 1ull));
        if (lane == 0) wcnt[wv] = (int)__popcll(mask);
        __syncthreads();
        int pre = 0, tot = 0;
#pragma unroll
        for (int i = 0; i < 16; ++i) {
            const int c = wcnt[i];
            pre += (i < wv) ? c : 0;
            tot += c;
        }
        if (m) tok_list[e * T_DIM + base + pre + wrank] = t;
        base += tot;
        __syncthreads();   // wcnt reused next round
    }
    if (tid == 0) counts[e * CNT_STRIDE] = base;
}

// ---------------------------------------------------------------------------
// MFMA GEMM 1: inter = silu(x@Wg) * (x@Wu). Tile 64 tok x (64g + 64u), BK=64.
// EXACT round-5 GEMM configuration (R6/R7: do not touch the K-loop).
// blockIdx.x = expert -> XCD affinity. blockIdx.z in [64,80) = down-proj
// transpose tiles (streaming filler; produces downT for gemm2).
// ---------------------------------------------------------------------------
__global__ __launch_bounds__(256) void gemm1_mfma_kernel(
    const half_t* __restrict__ xb, const half_t* __restrict__ gupT,
    const float* __restrict__ down, half_t* __restrict__ downT,
    const int* __restrict__ counts, const int* __restrict__ tok_list,
    half_t* __restrict__ inter)
{
    __shared__ __align__(16) char smraw[64 * 64 * 2 + 128 * 64 * 2 + 64 * 4];
    const int tid = threadIdx.x;
    const int e = blockIdx.x;              // expert == XCD affinity

    if (blockIdx.z >= 64) {  // down transpose: K = I = 512, N = H = 1024
        float (*tile)[65] = (float (*)[65])smraw;   // 64*65*4 = 16.6KB <= 24.8KB
        const float* se = down + (size_t)e * I_DIM * H_DIM;
        half_t* de = downT + (size_t)e * H_DIM * I_DIM;
        const int n0 = (blockIdx.z - 64) * 64, k0 = blockIdx.y * 64;
        const int c4 = (tid & 15) * 4, r0 = tid >> 4;
#pragma unroll
        for (int p = 0; p < 4; ++p) {
            const int r = r0 + p * 16;
            const float4 v = *(const float4*)&se[(size_t)(k0 + r) * H_DIM + n0 + c4];
            tile[r][c4 + 0] = v.x; tile[r][c4 + 1] = v.y;
            tile[r][c4 + 2] = v.z; tile[r][c4 + 3] = v.w;
        }
        __syncthreads();
#pragma unroll
        for (int p = 0; p < 4; ++p) {
            const int n = r0 + p * 16;
            const int kc = c4;
            halfx4 h = { (half_t)tile[kc + 0][n], (half_t)tile[kc + 1][n],
                         (half_t)tile[kc + 2][n], (half_t)tile[kc + 3][n] };
            *(halfx4*)&de[(size_t)(n0 + n) * I_DIM + k0 + kc] = h;
        }
        return;
    }

    const int count = counts[e * CNT_STRIDE];
    const int m0 = blockIdx.z * 64;
    if (m0 >= count) return;
    const int n0 = blockIdx.y * 64;        // gate col block

    half_t* const As = (half_t*)smraw;                      // 64x64
    half_t* const Bs = (half_t*)(smraw + 64 * 64 * 2);      // 128x64
    int* const toks = (int*)(smraw + 64 * 64 * 2 + 128 * 64 * 2);

    if (tid < 64) {
        const int m = m0 + tid;
        toks[tid] = (m < count) ? tok_list[e * T_DIM + m] : -1;
    }
    __syncthreads();

    const half_t* We = gupT + (size_t)e * (2 * I_DIM) * H_DIM;

    const int lane = tid & 63;
    const int w = tid >> 6;
    const int lr = lane >> 3, lc = lane & 7;

    // per-lane staging pointers (row fixed across K-loop)
    const half_t* aptr[2]; const half_t* bptr[4];
    half_t *alds[2], *blds[4];
#pragma unroll
    for (int j = 0; j < 2; ++j) {                 // A rows [w*16, w*16+16)
        const int r = w * 16 + j * 8 + lr;
        const int cg = lc ^ (r & 7);
        const int tk = toks[r];
        aptr[j] = xb + (size_t)(tk < 0 ? 0 : tk) * H_DIM + cg * 8;
        alds[j] = &As[(w * 16 + j * 8) * 64];
    }
#pragma unroll
    for (int j = 0; j < 4; ++j) {                 // B rows [w*32, w*32+32)
        const int n = w * 32 + j * 8 + lr;
        const int col = (n < 64) ? (n0 + n) : (I_DIM + n0 + (n - 64));
        const int cg = lc ^ (n & 7);
        bptr[j] = We + (size_t)col * H_DIM + cg * 8;
        blds[j] = &Bs[(w * 32 + j * 8) * 64];
    }

    const floatx4 fzero = {0.f, 0.f, 0.f, 0.f};
    floatx4 accg[2][2], accu[2][2];
#pragma unroll
    for (int i = 0; i < 2; ++i)
#pragma unroll
        for (int j = 0; j < 2; ++j) { accg[i][j] = fzero; accu[i][j] = fzero; }

    const int wr = w >> 1, wc = w & 1;
    const int fm = lane & 15, q = lane >> 4;
    const int fm7 = fm & 7;

    for (int k0 = 0; k0 < H_DIM; k0 += 64) {
#pragma unroll
        for (int j = 0; j < 2; ++j) GLOAD16(aptr[j] + k0, alds[j]);
#pragma unroll
        for (int j = 0; j < 4; ++j) GLOAD16(bptr[j] + k0, blds[j]);
        __syncthreads();

#pragma unroll
        for (int ks = 0; ks < 2; ++ks) {
            const int swz = ((ks * 4 + q) ^ fm7) * 8;   // halves
            const halfx8 a0 = *(const halfx8*)&As[(32 * wr + fm) * 64 + swz];
            const halfx8 a1 = *(const halfx8*)&As[(32 * wr + 16 + fm) * 64 + swz];
#pragma unroll
            for (int ct = 0; ct < 2; ++ct) {
                const int ng = wc * 32 + ct * 16 + fm;
                const halfx8 bg = *(const halfx8*)&Bs[ng * 64 + swz];
                const halfx8 bu = *(const halfx8*)&Bs[(64 + ng) * 64 + swz];
                accg[0][ct] = __builtin_amdgcn_mfma_f32_16x16x32_f16(a0, bg, accg[0][ct], 0, 0, 0);
                accg[1][ct] = __builtin_amdgcn_mfma_f32_16x16x32_f16(a1, bg, accg[1][ct], 0, 0, 0);
                accu[0][ct] = __builtin_amdgcn_mfma_f32_16x16x32_f16(a0, bu, accu[0][ct], 0, 0, 0);
                accu[1][ct] = __builtin_amdgcn_mfma_f32_16x16x32_f16(a1, bu, accu[1][ct], 0, 0, 0);
            }
        }
        __syncthreads();
    }

    // C/D layout: col = lane&15, row = q*4 + reg
#pragma unroll
    for (int rt = 0; rt < 2; ++rt)
#pragma unroll
        for (int r = 0; r < 4; ++r) {
            const int row = 32 * wr + 16 * rt + q * 4 + r;
            const int tk = toks[row];
            if (tk < 0) continue;
#pragma unroll
            for (int ct = 0; ct < 2; ++ct) {
                const float g = accg[rt][ct][r];
                const float u = accu[rt][ct][r];
                const float s = g / (1.f + __expf(-g)) * u;
                inter[(size_t)tk * I_DIM + n0 + wc * 32 + ct * 16 + fm] = (half_t)s;
            }
        }
}

// ---------------------------------------------------------------------------
// MFMA GEMM 2: out = inter @ down. Tile 64 x 128, BK=64, same staging scheme.
// EXACT round-5 configuration. Same expert==blockIdx.x XCD-affinity grid.
// ---------------------------------------------------------------------------
__global__ __launch_bounds__(256) void gemm2_mfma_kernel(
    const half_t* __restrict__ inter, const half_t* __restrict__ downT,
    const int* __restrict__ counts, const int* __restrict__ tok_list,
    float* __restrict__ out)
{
    const int e = blockIdx.x;              // expert == XCD affinity
    const int count = counts[e * CNT_STRIDE];
    const int m0 = blockIdx.z * 64;
    if (m0 >= count) return;
    const int n0 = blockIdx.y * 128;

    __shared__ __align__(16) half_t As[64 * 64];
    __shared__ __align__(16) half_t Bs[128 * 64];
    __shared__ int toks[64];

    const int tid = threadIdx.x;
    if (tid < 64) {
        const int m = m0 + tid;
        toks[tid] = (m < count) ? tok_list[e * T_DIM + m] : -1;
    }
    __syncthreads();

    const half_t* De = downT + (size_t)e * H_DIM * I_DIM;

    const int lane = tid & 63;
    const int w = tid >> 6;
    const int lr = lane >> 3, lc = lane & 7;

    const half_t* aptr[2]; const half_t* bptr[4];
    half_t *alds[2], *blds[4];
#pragma unroll
    for (int j = 0; j < 2; ++j) {
        const int r = w * 16 + j * 8 + lr;
        const int cg = lc ^ (r & 7);
        const int tk = toks[r];
        aptr[j] = inter + (size_t)(tk < 0 ? 0 : tk) * I_DIM + cg * 8;
        alds[j] = &As[(w * 16 + j * 8) * 64];
    }
#pragma unroll
    for (int j = 0; j < 4; ++j) {
        const int n = w * 32 + j * 8 + lr;
        const int cg = lc ^ (n & 7);
        bptr[j] = De + (size_t)(n0 + n) * I_DIM + cg * 8;
        blds[j] = &Bs[(w * 32 + j * 8) * 64];
    }

    const floatx4 fzero = {0.f, 0.f, 0.f, 0.f};
    floatx4 acc[2][4];
#pragma unroll
    for (int i = 0; i < 2; ++i)
#pragma unroll
        for (int j = 0; j < 4; ++j) acc[i][j] = fzero;

    const int wr = w >> 1, wc = w & 1;
    const int fm = lane & 15, q = lane >> 4;
    const int fm7 = fm & 7;

    for (int k0 = 0; k0 < I_DIM; k0 += 64) {
#pragma unroll
        for (int j = 0; j < 2; ++j) GLOAD16(aptr[j] + k0, alds[j]);
#pragma unroll
        for (int j = 0; j < 4; ++j) GLOAD16(bptr[j] + k0, blds[j]);
        __syncthreads();

#pragma unroll
        for (int ks = 0; ks < 2; ++ks) {
            const int swz = ((ks * 4 + q) ^ fm7) * 8;
            const halfx8 a0 = *(const halfx8*)&As[(32 * wr + fm) * 64 + swz];
            const halfx8 a1 = *(const halfx8*)&As[(32 * wr + 16 + fm) * 64 + swz];
#pragma unroll
            for (int ct = 0; ct < 4; ++ct) {
                const halfx8 b = *(const halfx8*)&Bs[(wc * 64 + ct * 16 + fm) * 64 + swz];
                acc[0][ct] = __builtin_amdgcn_mfma_f32_16x16x32_f16(a0, b, acc[0][ct], 0, 0, 0);
                acc[1][ct] = __builtin_amdgcn_mfma_f32_16x16x32_f16(a1, b, acc[1][ct], 0, 0, 0);
            }
        }
        __syncthreads();
    }

#pragma unroll
    for (int rt = 0; rt < 2; ++rt)
#pragma unroll
        for (int r = 0; r < 4; ++r) {
            const int row = 32 * wr + 16 * rt + q * 4 + r;
            const int tk = toks[row];
            if (tk < 0) continue;
#pragma unroll
            for (int ct = 0; ct < 4; ++ct)
                out[(size_t)tk * H_DIM + n0 + wc * 64 + ct * 16 + fm] = acc[rt][ct][r];
        }
}

// ---------------------------------------------------------------------------
extern "C" void kernel_launch(void* const* d_in, const int* in_sizes, int n_in,
                              void* d_out, int out_size, void* d_ws, size_t ws_size,
                              hipStream_t stream)
{
    const float* x         = (const float*)d_in[0];
    const int*   token_ids = (const int*)  d_in[1];
    const float* mu        = (const float*)d_in[2];
    const float* down      = (const float*)d_in[4];
    const float* gup       = (const float*)d_in[3];
    const float* mu_w      = (const float*)d_in[5];
    float* out = (float*)d_out;

    char* ws = (char*)d_ws;
    int*    counts    = (int*)(ws + OFF_COUNTS);
    int*    expert_id = (int*)(ws + OFF_EID);
    int*    tok_list  = (int*)(ws + OFF_TOKL);
    half_t* xb        = (half_t*)(ws + OFF_XB);
    half_t* gupT      = (half_t*)(ws + OFF_GUPT);
    half_t* downT     = (half_t*)(ws + OFF_DOWNT);
    half_t* inter     = (half_t*)(ws + OFF_INTER);

    // grid (8,256,4): bx == XCD. z=0: gup transpose. z=1: x->f16.
    // z=2..3: routing (1 block/token).
    prep_kernel<<<dim3(8, 256, 4), 256, 0, stream>>>(
        x, gup, mu, token_ids, mu_w, xb, gupT, expert_id);
    // zero-atomic scatter: one block per expert; counts plain-stored
    // (no memset dispatch needed anymore).
    scatter_kernel<<<E_DIM, 1024, 0, stream>>>(expert_id, counts, tok_list);
    // z<64: gemm m-blocks (early-exit past count); z in [64,80): down-proj
    // transpose tiles overlapped with the gemm. expert on blockIdx.x =>
    // consecutive linear ids round-robin the 8 XCDs, pinning expert e to XCD e.
    gemm1_mfma_kernel<<<dim3(E_DIM, 8, 80), 256, 0, stream>>>(
        xb, gupT, down, downT, counts, tok_list, inter);
    gemm2_mfma_kernel<<<dim3(E_DIM, 8, T_DIM / 64), 256, 0, stream>>>(
        inter, downT, counts, tok_list, out);
}

// Round 6
// 156.740 us; speedup vs baseline: 1.0299x; 1.0118x over previous
//
#include <hip/hip_runtime.h>
#include <cmath>

// Problem constants (fixed by the reference)
constexpr int T_DIM = 4096;
constexpr int H_DIM = 1024;
constexpr int E_DIM = 8;
constexpr int I_DIM = 512;   // 4096 / 8
constexpr int V_DIM = 32000;

typedef _Float16 half_t;
typedef __attribute__((ext_vector_type(8))) _Float16 halfx8;
typedef __attribute__((ext_vector_type(4))) _Float16 halfx4;
typedef __attribute__((ext_vector_type(4))) float floatx4;

// async global->LDS, 16 B per lane; LDS dest is wave-uniform base + lane*16
#define GLOAD16(g, l)                                                        \
    __builtin_amdgcn_global_load_lds(                                        \
        (const __attribute__((address_space(1))) void*)(g),                  \
        (__attribute__((address_space(3))) void*)(l), 16, 0, 0)

// ---------------------------------------------------------------------------
// Workspace layout (bytes)
// ---------------------------------------------------------------------------
constexpr int  CNT_STRIDE  = 16;                                          // ints
constexpr size_t OFF_COUNTS = 0;                                          // E*16 ints (512 B)
constexpr size_t OFF_EID    = 1024;                                       // T ints (16 KB)
constexpr size_t OFF_TOKL   = OFF_EID + (size_t)T_DIM * 4;                // E*T ints (128 KB)
constexpr size_t OFF_XB     = OFF_TOKL + (size_t)E_DIM * T_DIM * 4;       // T*H f16 (8 MB)
constexpr size_t OFF_GUPT   = OFF_XB + (size_t)T_DIM * H_DIM * 2;         // E*2I*H f16 (16 MB)
constexpr size_t OFF_DOWNT  = OFF_GUPT + (size_t)E_DIM * 2 * I_DIM * H_DIM * 2; // E*H*I f16 (8 MB)
constexpr size_t OFF_INTER  = OFF_DOWNT + (size_t)E_DIM * H_DIM * I_DIM * 2;    // T*I f16 (4 MB)

// ---------------------------------------------------------------------------
// Prep: one launch, grid (8, 256, 4). blockIdx.x round-robins the 8 XCDs.
//   z == 0      : gup transpose, expert = bx (XCD-affine producer; R4 neutral,
//                 harmless — kept).
//   z == 1      : x -> f16 convert (512 blocks x 4 x 2048 floats).
//   z in [2,4)  : routing logits, ONE BLOCK PER TOKEN (R1 post-mortem: multi-
//                 token blocks serialize mu loads -> 86us latency-bound).
// Down-transpose lives in gemm1's launch (z>=64 there).
// ---------------------------------------------------------------------------
__global__ __launch_bounds__(256) void prep_kernel(
    const float* __restrict__ x, const float* __restrict__ gup,
    const float* __restrict__ mu, const int* __restrict__ token_ids,
    const float* __restrict__ mu_w, half_t* __restrict__ xb,
    half_t* __restrict__ gupT, int* __restrict__ expert_id)
{
    const int z = blockIdx.z, bx = blockIdx.x, by = blockIdx.y;
    const int tid = threadIdx.x;

    if (z >= 2) {  // routing logits: one block per token
        const int t = ((z - 2) * 256 + by) * 8 + bx;

        const float4 m = *(const float4*)&mu[(size_t)t * H_DIM + tid * 4];
        float acc[E_DIM];
#pragma unroll
        for (int e = 0; e < E_DIM; ++e) {
            const float4 w = *(const float4*)&mu_w[e * H_DIM + tid * 4];
            acc[e] = m.x * w.x + m.y * w.y + m.z * w.z + m.w * w.w;
        }
#pragma unroll
        for (int e = 0; e < E_DIM; ++e) {
#pragma unroll
            for (int off = 32; off > 0; off >>= 1)
                acc[e] += __shfl_down(acc[e], off, 64);
        }
        __shared__ float part[4][E_DIM];
        const int lane = tid & 63, w = tid >> 6;
        if (lane == 0) {
#pragma unroll
            for (int e = 0; e < E_DIM; ++e) part[w][e] = acc[e];
        }
        __syncthreads();
        if (tid == 0) {
            int tk = token_ids[t];
            tk = min(max(tk, 0), V_DIM - 1);
            const int be = tk & (E_DIM - 1);
            float best = -1e30f; int bi = 0;
#pragma unroll
            for (int e = 0; e < E_DIM; ++e) {
                const float c = part[0][e] + part[1][e] + part[2][e] + part[3][e]
                              + (e == be ? 10.f : 0.f);
                if (c > best) { best = c; bi = e; }  // strict > = first max (jnp.argmax)
            }
            expert_id[t] = bi;
        }
        return;
    }

    if (z == 1) {  // convert x -> f16: 512 blocks x 8192 floats (4 x 2048)
        const int idx = by * 8 + bx;
        if (idx >= 512) return;
#pragma unroll
        for (int p = 0; p < 4; ++p) {
            const size_t i = (size_t)idx * 8192 + p * 2048 + tid * 8;
            const float4 v0 = *(const float4*)&x[i];
            const float4 v1 = *(const float4*)&x[i + 4];
            halfx8 h = { (half_t)v0.x, (half_t)v0.y, (half_t)v0.z, (half_t)v0.w,
                         (half_t)v1.x, (half_t)v1.y, (half_t)v1.z, (half_t)v1.w };
            *(halfx8*)&xb[i] = h;
        }
        return;
    }

    // z == 0: gup transpose, e = bx (== XCD). K = H = 1024, N = 2I = 1024.
    __shared__ float tile[64][65];
    const float* se = gup + (size_t)bx * H_DIM * (2 * I_DIM);
    half_t* de = gupT + (size_t)bx * (2 * I_DIM) * H_DIM;
    constexpr int N = 1024, K = H_DIM;
    const int n0 = (by & 15) * 64, k0 = (by >> 4) * 64;
    const int c4 = (tid & 15) * 4, r0 = tid >> 4;
#pragma unroll
    for (int p = 0; p < 4; ++p) {
        const int r = r0 + p * 16;
        const float4 v = *(const float4*)&se[(size_t)(k0 + r) * N + n0 + c4];
        tile[r][c4 + 0] = v.x; tile[r][c4 + 1] = v.y;
        tile[r][c4 + 2] = v.z; tile[r][c4 + 3] = v.w;
    }
    __syncthreads();
#pragma unroll
    for (int p = 0; p < 4; ++p) {
        const int n = r0 + p * 16;
        const int kc = c4;
        halfx4 h = { (half_t)tile[kc + 0][n], (half_t)tile[kc + 1][n],
                     (half_t)tile[kc + 2][n], (half_t)tile[kc + 3][n] };
        *(halfx4*)&de[(size_t)(n0 + n) * K + k0 + kc] = h;
    }
}

// ---------------------------------------------------------------------------
// Scatter, zero-atomic (R5 win, -3us): one block per expert, 1024 threads,
// ballot + wave-count LDS prefix; counts plain-stored, no memset needed.
// ---------------------------------------------------------------------------
__global__ __launch_bounds__(1024) void scatter_kernel(
    const int* __restrict__ expert_id, int* __restrict__ counts,
    int* __restrict__ tok_list)
{
    const int e = blockIdx.x;
    const int tid = threadIdx.x;
    const int lane = tid & 63, wv = tid >> 6;   // 16 waves
    __shared__ int wcnt[16];
    int base = 0;
#pragma unroll
    for (int r = 0; r < 4; ++r) {
        const int t = r * 1024 + tid;
        const bool m = (expert_id[t] == e);
        const unsigned long long mask = __ballot(m);
        const int wrank = (int)__popcll(mask & ((1ull << lane) - 1ull));
        if (lane == 0) wcnt[wv] = (int)__popcll(mask);
        __syncthreads();
        int pre = 0, tot = 0;
#pragma unroll
        for (int i = 0; i < 16; ++i) {
            const int c = wcnt[i];
            pre += (i < wv) ? c : 0;
            tot += c;
        }
        if (m) tok_list[e * T_DIM + base + pre + wrank] = t;
        base += tot;
        __syncthreads();   // wcnt reused next round
    }
    if (tid == 0) counts[e * CNT_STRIDE] = base;
}

// ---------------------------------------------------------------------------
// MFMA GEMM 1: inter = silu(x@Wg) * (x@Wu). Tile 64 tok x (64g + 64u).
// ROUND-6 CHANGE: 2-phase double-buffered K-loop (T3-minimum). The R5 loop
// exposed full load latency every K-step (GLOAD -> barrier[vmcnt0] -> MFMA
// -> barrier: ~25% duty, GEMMs ~6% of peak by cross-round subtraction).
// Here: stage K-step t+1 into buf^1 BEFORE computing t; ONE barrier/iter
// whose compiler-emitted vmcnt(0) waits on loads that had the whole MFMA
// phase to land. NO inline asm (prior session's R7 failure used manual
// waitcnt asm = rule-18 poison); buffer parity static via x2 unroll
// (rule-20: no runtime-indexed pointer arrays). LDS 49.4KB -> 3 blocks/CU
// (grid provides ~2 gemm blocks/CU, unharmed).
// blockIdx.x = expert -> XCD affinity. blockIdx.z in [64,80) = down-proj
// transpose tiles (streaming filler; produces downT for gemm2).
// ---------------------------------------------------------------------------
__global__ __launch_bounds__(256) void gemm1_mfma_kernel(
    const half_t* __restrict__ xb, const half_t* __restrict__ gupT,
    const float* __restrict__ down, half_t* __restrict__ downT,
    const int* __restrict__ counts, const int* __restrict__ tok_list,
    half_t* __restrict__ inter)
{
    // As0 | As1 | Bs0 | Bs1 | toks  = 8K+8K+16K+16K+256
    __shared__ __align__(16) char smraw[49152 + 64 * 4];
    const int tid = threadIdx.x;
    const int e = blockIdx.x;              // expert == XCD affinity

    if (blockIdx.z >= 64) {  // down transpose: K = I = 512, N = H = 1024
        float (*tile)[65] = (float (*)[65])smraw;   // 16.6KB <= 49.4KB
        const float* se = down + (size_t)e * I_DIM * H_DIM;
        half_t* de = downT + (size_t)e * H_DIM * I_DIM;
        const int n0 = (blockIdx.z - 64) * 64, k0 = blockIdx.y * 64;
        const int c4 = (tid & 15) * 4, r0 = tid >> 4;
#pragma unroll
        for (int p = 0; p < 4; ++p) {
            const int r = r0 + p * 16;
            const float4 v = *(const float4*)&se[(size_t)(k0 + r) * H_DIM + n0 + c4];
            tile[r][c4 + 0] = v.x; tile[r][c4 + 1] = v.y;
            tile[r][c4 + 2] = v.z; tile[r][c4 + 3] = v.w;
        }
        __syncthreads();
#pragma unroll
        for (int p = 0; p < 4; ++p) {
            const int n = r0 + p * 16;
            const int kc = c4;
            halfx4 h = { (half_t)tile[kc + 0][n], (half_t)tile[kc + 1][n],
                         (half_t)tile[kc + 2][n], (half_t)tile[kc + 3][n] };
            *(halfx4*)&de[(size_t)(n0 + n) * I_DIM + k0 + kc] = h;
        }
        return;
    }

    const int count = counts[e * CNT_STRIDE];
    const int m0 = blockIdx.z * 64;
    if (m0 >= count) return;
    const int n0 = blockIdx.y * 64;        // gate col block

    half_t* const As0 = (half_t*)smraw;                     // 64x64
    half_t* const As1 = (half_t*)(smraw + 8192);
    half_t* const Bs0 = (half_t*)(smraw + 16384);           // 128x64
    half_t* const Bs1 = (half_t*)(smraw + 32768);
    int* const toks = (int*)(smraw + 49152);

    if (tid < 64) {
        const int m = m0 + tid;
        toks[tid] = (m < count) ? tok_list[e * T_DIM + m] : -1;
    }
    __syncthreads();

    const half_t* We = gupT + (size_t)e * (2 * I_DIM) * H_DIM;

    const int lane = tid & 63;
    const int w = tid >> 6;
    const int lr = lane >> 3, lc = lane & 7;

    // per-lane staging pointers (row fixed across K-loop)
    const half_t* aptr[2]; const half_t* bptr[4];
    half_t *a0l[2], *a1l[2], *b0l[4], *b1l[4];
#pragma unroll
    for (int j = 0; j < 2; ++j) {                 // A rows [w*16, w*16+16)
        const int r = w * 16 + j * 8 + lr;
        const int cg = lc ^ (r & 7);
        const int tk = toks[r];
        aptr[j] = xb + (size_t)(tk < 0 ? 0 : tk) * H_DIM + cg * 8;
        const int off = (w * 16 + j * 8) * 64;
        a0l[j] = As0 + off; a1l[j] = As1 + off;
    }
#pragma unroll
    for (int j = 0; j < 4; ++j) {                 // B rows [w*32, w*32+32)
        const int n = w * 32 + j * 8 + lr;
        const int col = (n < 64) ? (n0 + n) : (I_DIM + n0 + (n - 64));
        const int cg = lc ^ (n & 7);
        bptr[j] = We + (size_t)col * H_DIM + cg * 8;
        const int off = (w * 32 + j * 8) * 64;
        b0l[j] = Bs0 + off; b1l[j] = Bs1 + off;
    }

    const floatx4 fzero = {0.f, 0.f, 0.f, 0.f};
    floatx4 accg[2][2], accu[2][2];
#pragma unroll
    for (int i = 0; i < 2; ++i)
#pragma unroll
        for (int j = 0; j < 2; ++j) { accg[i][j] = fzero; accu[i][j] = fzero; }

    const int wr = w >> 1, wc = w & 1;
    const int fm = lane & 15, q = lane >> 4;
    const int fm7 = fm & 7;

    auto mfma_phase = [&](const half_t* A_, const half_t* B_) {
#pragma unroll
        for (int ks = 0; ks < 2; ++ks) {
            const int swz = ((ks * 4 + q) ^ fm7) * 8;   // halves
            const halfx8 a0 = *(const halfx8*)&A_[(32 * wr + fm) * 64 + swz];
            const halfx8 a1 = *(const halfx8*)&A_[(32 * wr + 16 + fm) * 64 + swz];
#pragma unroll
            for (int ct = 0; ct < 2; ++ct) {
                const int ng = wc * 32 + ct * 16 + fm;
                const halfx8 bg = *(const halfx8*)&B_[ng * 64 + swz];
                const halfx8 bu = *(const halfx8*)&B_[(64 + ng) * 64 + swz];
                accg[0][ct] = __builtin_amdgcn_mfma_f32_16x16x32_f16(a0, bg, accg[0][ct], 0, 0, 0);
                accg[1][ct] = __builtin_amdgcn_mfma_f32_16x16x32_f16(a1, bg, accg[1][ct], 0, 0, 0);
                accu[0][ct] = __builtin_amdgcn_mfma_f32_16x16x32_f16(a0, bu, accu[0][ct], 0, 0, 0);
                accu[1][ct] = __builtin_amdgcn_mfma_f32_16x16x32_f16(a1, bu, accu[1][ct], 0, 0, 0);
            }
        }
    };

    // prologue: stage k=0 into buf0
#pragma unroll
    for (int j = 0; j < 2; ++j) GLOAD16(aptr[j], a0l[j]);
#pragma unroll
    for (int j = 0; j < 4; ++j) GLOAD16(bptr[j], b0l[j]);
    __syncthreads();

    for (int it = 0; it < H_DIM / 64; it += 2) {
        const int k1 = (it + 1) * 64;
        if (k1 < H_DIM) {   // stage next into buf1 while computing buf0
#pragma unroll
            for (int j = 0; j < 2; ++j) GLOAD16(aptr[j] + k1, a1l[j]);
#pragma unroll
            for (int j = 0; j < 4; ++j) GLOAD16(bptr[j] + k1, b1l[j]);
        }
        mfma_phase(As0, Bs0);
        __syncthreads();    // drains buf1 stage; protects buf0 reuse
        const int k2 = (it + 2) * 64;
        if (k2 < H_DIM) {   // stage next into buf0 while computing buf1
#pragma unroll
            for (int j = 0; j < 2; ++j) GLOAD16(aptr[j] + k2, a0l[j]);
#pragma unroll
            for (int j = 0; j < 4; ++j) GLOAD16(bptr[j] + k2, b0l[j]);
        }
        mfma_phase(As1, Bs1);
        __syncthreads();
    }

    // C/D layout: col = lane&15, row = q*4 + reg
#pragma unroll
    for (int rt = 0; rt < 2; ++rt)
#pragma unroll
        for (int r = 0; r < 4; ++r) {
            const int row = 32 * wr + 16 * rt + q * 4 + r;
            const int tk = toks[row];
            if (tk < 0) continue;
#pragma unroll
            for (int ct = 0; ct < 2; ++ct) {
                const float g = accg[rt][ct][r];
                const float u = accu[rt][ct][r];
                const float s = g / (1.f + __expf(-g)) * u;
                inter[(size_t)tk * I_DIM + n0 + wc * 32 + ct * 16 + fm] = (half_t)s;
            }
        }
}

// ---------------------------------------------------------------------------
// MFMA GEMM 2: out = inter @ down. Tile 64 x 128. Same round-6 2-phase
// double-buffered K-loop as gemm1 (8 K-steps). Same XCD-affinity grid.
// ---------------------------------------------------------------------------
__global__ __launch_bounds__(256) void gemm2_mfma_kernel(
    const half_t* __restrict__ inter, const half_t* __restrict__ downT,
    const int* __restrict__ counts, const int* __restrict__ tok_list,
    float* __restrict__ out)
{
    const int e = blockIdx.x;              // expert == XCD affinity
    const int count = counts[e * CNT_STRIDE];
    const int m0 = blockIdx.z * 64;
    if (m0 >= count) return;
    const int n0 = blockIdx.y * 128;

    __shared__ __align__(16) char smraw[49152 + 64 * 4];
    half_t* const As0 = (half_t*)smraw;
    half_t* const As1 = (half_t*)(smraw + 8192);
    half_t* const Bs0 = (half_t*)(smraw + 16384);
    half_t* const Bs1 = (half_t*)(smraw + 32768);
    int* const toks = (int*)(smraw + 49152);

    const int tid = threadIdx.x;
    if (tid < 64) {
        const int m = m0 + tid;
        toks[tid] = (m < count) ? tok_list[e * T_DIM + m] : -1;
    }
    __syncthreads();

    const half_t* De = downT + (size_t)e * H_DIM * I_DIM;

    const int lane = tid & 63;
    const int w = tid >> 6;
    const int lr = lane >> 3, lc = lane & 7;

    const half_t* aptr[2]; const half_t* bptr[4];
    half_t *a0l[2], *a1l[2], *b0l[4], *b1l[4];
#pragma unroll
    for (int j = 0; j < 2; ++j) {
        const int r = w * 16 + j * 8 + lr;
        const int cg = lc ^ (r & 7);
        const int tk = toks[r];
        aptr[j] = inter + (size_t)(tk < 0 ? 0 : tk) * I_DIM + cg * 8;
        const int off = (w * 16 + j * 8) * 64;
        a0l[j] = As0 + off; a1l[j] = As1 + off;
    }
#pragma unroll
    for (int j = 0; j < 4; ++j) {
        const int n = w * 32 + j * 8 + lr;
        const int cg = lc ^ (n & 7);
        bptr[j] = De + (size_t)(n0 + n) * I_DIM + cg * 8;
        const int off = (w * 32 + j * 8) * 64;
        b0l[j] = Bs0 + off; b1l[j] = Bs1 + off;
    }

    const floatx4 fzero = {0.f, 0.f, 0.f, 0.f};
    floatx4 acc[2][4];
#pragma unroll
    for (int i = 0; i < 2; ++i)
#pragma unroll
        for (int j = 0; j < 4; ++j) acc[i][j] = fzero;

    const int wr = w >> 1, wc = w & 1;
    const int fm = lane & 15, q = lane >> 4;
    const int fm7 = fm & 7;

    auto mfma_phase = [&](const half_t* A_, const half_t* B_) {
#pragma unroll
        for (int ks = 0; ks < 2; ++ks) {
            const int swz = ((ks * 4 + q) ^ fm7) * 8;
            const halfx8 a0 = *(const halfx8*)&A_[(32 * wr + fm) * 64 + swz];
            const halfx8 a1 = *(const halfx8*)&A_[(32 * wr + 16 + fm) * 64 + swz];
#pragma unroll
            for (int ct = 0; ct < 4; ++ct) {
                const halfx8 b = *(const halfx8*)&B_[(wc * 64 + ct * 16 + fm) * 64 + swz];
                acc[0][ct] = __builtin_amdgcn_mfma_f32_16x16x32_f16(a0, b, acc[0][ct], 0, 0, 0);
                acc[1][ct] = __builtin_amdgcn_mfma_f32_16x16x32_f16(a1, b, acc[1][ct], 0, 0, 0);
            }
        }
    };

    // prologue: stage k=0 into buf0
#pragma unroll
    for (int j = 0; j < 2; ++j) GLOAD16(aptr[j], a0l[j]);
#pragma unroll
    for (int j = 0; j < 4; ++j) GLOAD16(bptr[j], b0l[j]);
    __syncthreads();

    for (int it = 0; it < I_DIM / 64; it += 2) {
        const int k1 = (it + 1) * 64;
        if (k1 < I_DIM) {
#pragma unroll
            for (int j = 0; j < 2; ++j) GLOAD16(aptr[j] + k1, a1l[j]);
#pragma unroll
            for (int j = 0; j < 4; ++j) GLOAD16(bptr[j] + k1, b1l[j]);
        }
        mfma_phase(As0, Bs0);
        __syncthreads();
        const int k2 = (it + 2) * 64;
        if (k2 < I_DIM) {
#pragma unroll
            for (int j = 0; j < 2; ++j) GLOAD16(aptr[j] + k2, a0l[j]);
#pragma unroll
            for (int j = 0; j < 4; ++j) GLOAD16(bptr[j] + k2, b0l[j]);
        }
        mfma_phase(As1, Bs1);
        __syncthreads();
    }

#pragma unroll
    for (int rt = 0; rt < 2; ++rt)
#pragma unroll
        for (int r = 0; r < 4; ++r) {
            const int row = 32 * wr + 16 * rt + q * 4 + r;
            const int tk = toks[row];
            if (tk < 0) continue;
#pragma unroll
            for (int ct = 0; ct < 4; ++ct)
                out[(size_t)tk * H_DIM + n0 + wc * 64 + ct * 16 + fm] = acc[rt][ct][r];
        }
}

// ---------------------------------------------------------------------------
extern "C" void kernel_launch(void* const* d_in, const int* in_sizes, int n_in,
                              void* d_out, int out_size, void* d_ws, size_t ws_size,
                              hipStream_t stream)
{
    const float* x         = (const float*)d_in[0];
    const int*   token_ids = (const int*)  d_in[1];
    const float* mu        = (const float*)d_in[2];
    const float* gup       = (const float*)d_in[3];
    const float* down      = (const float*)d_in[4];
    const float* mu_w      = (const float*)d_in[5];
    float* out = (float*)d_out;

    char* ws = (char*)d_ws;
    int*    counts    = (int*)(ws + OFF_COUNTS);
    int*    expert_id = (int*)(ws + OFF_EID);
    int*    tok_list  = (int*)(ws + OFF_TOKL);
    half_t* xb        = (half_t*)(ws + OFF_XB);
    half_t* gupT      = (half_t*)(ws + OFF_GUPT);
    half_t* downT     = (half_t*)(ws + OFF_DOWNT);
    half_t* inter     = (half_t*)(ws + OFF_INTER);

    // grid (8,256,4): bx == XCD. z=0: gup transpose. z=1: x->f16.
    // z=2..3: routing (1 block/token).
    prep_kernel<<<dim3(8, 256, 4), 256, 0, stream>>>(
        x, gup, mu, token_ids, mu_w, xb, gupT, expert_id);
    // zero-atomic scatter: one block per expert.
    scatter_kernel<<<E_DIM, 1024, 0, stream>>>(expert_id, counts, tok_list);
    // z<64: gemm m-blocks (early-exit past count); z in [64,80): down-proj
    // transpose tiles overlapped with the gemm.
    gemm1_mfma_kernel<<<dim3(E_DIM, 8, 80), 256, 0, stream>>>(
        xb, gupT, down, downT, counts, tok_list, inter);
    gemm2_mfma_kernel<<<dim3(E_DIM, 8, T_DIM / 64), 256, 0, stream>>>(
        inter, downT, counts, tok_list, out);
}